// Round 10
// baseline (137.127 us; speedup 1.0000x reference)
//
#include <hip/hip_runtime.h>

#define M_ 4
#define K_ 2048
#define D_ 32
#define HW_ 4096
#define NHW_ 32768

// Gap-test margin: conf <=> b1m - b2m > GAPEPS, GAPEPS >= 2*eps where eps is
// the hard bound on |s~ - s_exact| for the 3-term bf16 split: dropped lo*lo
// term <= 2^-16*||q||*||c|| <= ~9e-4 + fp32 MFMA accum ~4e-4 => eps <= 1.3e-3.
// GAPEPS = 0.01 ~ 4x margin (same margin ratio HW-validated in R6-R8).
// conf => for all k != K1: s_exact(k) <= s~(k)+eps <= b2m+eps < b1m-eps
//         <= s~(K1)... i.e. K1 is the unique exact argmax.
#define GAPEPS 0.01f

// workspace (bytes)
#define CH_OFF 0                        // bf16 hi codebook [4][2048][32] (512 KiB)
#define CL_OFF (M_*K_*D_*2)             // bf16 lo codebook              (512 KiB)
#define HN_OFF (CL_OFF*2)               // f32 -0.5*||c||^2 [4][2048]    (32 KiB)
#define CNT_OFF (HN_OFF + M_*K_*4)      // i32 unconfirmed count         (16 B)
#define LIST_OFF (CNT_OFF + 16)         // i32 unconfirmed ids [4*32768] (512 KiB)

typedef __attribute__((ext_vector_type(8))) short bf16x8;
typedef __attribute__((ext_vector_type(4))) float f32x4;

__device__ __forceinline__ short bf16_rte(float x, float* back) {
    unsigned u = __float_as_uint(x);
    unsigned r = (u + 0x7FFFu + ((u >> 16) & 1u)) >> 16;
    *back = __uint_as_float(r << 16);
    return (short)(r & 0xFFFFu);
}

// ---- kernel 1: codebook -> bf16 hi/lo + (-0.5*||c||^2); zero fallback cnt ----
// (R8-validated, unchanged)
__global__ __launch_bounds__(256) void prep_kernel(const float* __restrict__ cb,
                                                   unsigned char* __restrict__ ws) {
    if (blockIdx.x == 0 && threadIdx.x == 0) *(int*)(ws + CNT_OFF) = 0;
    int t = blockIdx.x * 256 + threadIdx.x;          // row id = m*K_ + k
    const float* src = cb + (size_t)t * D_;
    short* dh = (short*)(ws + CH_OFF) + (size_t)t * D_;
    short* dl = (short*)(ws + CL_OFF) + (size_t)t * D_;
    float* hn = (float*)(ws + HN_OFF);
    bf16x8 vh[4], vl[4];
    float c2 = 0.f;
    #pragma unroll
    for (int d = 0; d < D_; ++d) {
        float x = src[d];
        float hf, lf;
        short hb = bf16_rte(x, &hf);
        short lb = bf16_rte(x - hf, &lf);
        vh[d >> 3][d & 7] = hb;
        vl[d >> 3][d & 7] = lb;
        c2 = fmaf(x, x, c2);
    }
    #pragma unroll
    for (int i = 0; i < 4; ++i) {
        *(bf16x8*)(dh + i * 8) = vh[i];
        *(bf16x8*)(dl + i * 8) = vl[i];
    }
    hn[t] = -0.5f * c2;
}

__device__ __forceinline__ float score_fp32(const float* __restrict__ q,
                                            const float4* __restrict__ c) {
    float d0 = 0, d1 = 0, d2 = 0, d3 = 0, e0 = 0, e1 = 0, e2 = 0, e3 = 0;
    #pragma unroll
    for (int v = 0; v < 8; ++v) {
        float4 cv = c[v];
        d0 = fmaf(q[v * 4 + 0], cv.x, d0);
        d1 = fmaf(q[v * 4 + 1], cv.y, d1);
        d2 = fmaf(q[v * 4 + 2], cv.z, d2);
        d3 = fmaf(q[v * 4 + 3], cv.w, d3);
        e0 = fmaf(cv.x, cv.x, e0);
        e1 = fmaf(cv.y, cv.y, e1);
        e2 = fmaf(cv.z, cv.z, e2);
        e3 = fmaf(cv.w, cv.w, e3);
    }
    return ((d0 + d1) + (d2 + d3)) - 0.5f * ((e0 + e1) + (e2 + e3));
}

// ---- kernel 2: 3-term MFMA + top1(idx)/top2(val) [R8-validated math],
//      32-position tiles (2x grid for occupancy), fused gap-test epilogue ----
// 512 threads = 8 waves. wave w: m = w&3, kh = w>>2 (half of the codebook).
__global__ __launch_bounds__(512, 8) void score_kernel(
        const float* __restrict__ latent,
        const unsigned char* __restrict__ cws,
        int* __restrict__ cnt, int* __restrict__ list,
        int* __restrict__ out) {
    __shared__ float s_b1[2][M_][32];
    __shared__ int   s_k1[2][M_][32];
    __shared__ float s_b2[2][M_][32];

    const int tid  = threadIdx.x;
    const int wave = tid >> 6;
    const int L    = tid & 63;
    const int m    = wave & 3;
    const int kh   = wave >> 2;
    const int col  = L & 15;
    const int krow = L >> 4;
    const int posbase = blockIdx.x * 32;          // 32-pos tile (4096 % 32 == 0)
    const int n   = posbase >> 12;
    const int hwb = posbase & (HW_ - 1);

    // q -> bf16 hi/lo B-fragments, 2 position groups of 16 (R8 pattern, G=2)
    bf16x8 qh[2], ql[2];
    const float* lp = latent + ((size_t)n * (M_ * D_) + m * D_) * HW_ + hwb;
    #pragma unroll
    for (int g = 0; g < 2; ++g)
        #pragma unroll
        for (int j = 0; j < 8; ++j) {
            float x = lp[(size_t)(krow * 8 + j) * HW_ + g * 16 + col];
            float hf, lf;
            qh[g][j] = bf16_rte(x, &hf);
            ql[g][j] = bf16_rte(x - hf, &lf);
        }

    const short* ah = (const short*)(cws + CH_OFF)
                      + ((size_t)m * K_ + kh * 1024 + col) * D_ + krow * 8;
    const short* al = (const short*)(cws + CL_OFF)
                      + ((size_t)m * K_ + kh * 1024 + col) * D_ + krow * 8;
    const float* hn = (const float*)(cws + HN_OFF) + m * K_ + kh * 1024 + krow * 4;

    float b1[2], b2[2];
    int   k1[2];
    #pragma unroll
    for (int g = 0; g < 2; ++g) { b1[g] = b2[g] = -3.402823466e+38f; k1[g] = 0; }

    const int kbase = kh * 1024 + krow * 4;

    #pragma unroll 2
    for (int t = 0; t < 64; ++t) {
        bf16x8 ch = *(const bf16x8*)(ah + (size_t)t * (16 * D_));
        bf16x8 cl = *(const bf16x8*)(al + (size_t)t * (16 * D_));
        f32x4  c0 = *(const f32x4*)(hn + t * 16);
        const int kt = kbase + t * 16;
        #pragma unroll
        for (int g = 0; g < 2; ++g) {
            f32x4 a = __builtin_amdgcn_mfma_f32_16x16x32_bf16(cl, qh[g], c0, 0, 0, 0);
            a = __builtin_amdgcn_mfma_f32_16x16x32_bf16(ch, ql[g], a, 0, 0, 0);
            a = __builtin_amdgcn_mfma_f32_16x16x32_bf16(ch, qh[g], a, 0, 0, 0);
            #pragma unroll
            for (int r = 0; r < 4; ++r) {
                float s = a[r];
                b2[g] = __builtin_amdgcn_fmed3f(b1[g], b2[g], s);   // running 2nd-max
                bool gt = s > b1[g];                                // strict: first-max
                k1[g] = gt ? (kt + r) : k1[g];
                b1[g] = gt ? s : b1[g];
            }
        }
    }

    // in-wave butterfly merge over the 4 code-row lane-groups (R8-validated)
    #pragma unroll
    for (int g = 0; g < 2; ++g) {
        #pragma unroll
        for (int off = 16; off <= 32; off <<= 1) {
            float ob1 = __shfl_xor(b1[g], off);
            int   ok1 = __shfl_xor(k1[g], off);
            float ob2 = __shfl_xor(b2[g], off);
            float mn  = fminf(b1[g], ob1);
            b2[g] = fmaxf(mn, fmaxf(b2[g], ob2));
            bool awin = (b1[g] > ob1) || (b1[g] == ob1 && k1[g] < ok1);
            b1[g] = awin ? b1[g] : ob1;
            k1[g] = awin ? k1[g] : ok1;
        }
    }
    if (L < 16) {
        #pragma unroll
        for (int g = 0; g < 2; ++g) {
            s_b1[kh][m][g * 16 + L] = b1[g];
            s_k1[kh][m][g * 16 + L] = k1[g];
            s_b2[kh][m][g * 16 + L] = b2[g];
        }
    }
    __syncthreads();

    // fused epilogue: merge k-halves, gap test, write out, append unconfirmed
    if (tid < 128) {                      // waves 0-1 fully active
        const int mm = tid >> 5;          // 0..3
        const int pl = tid & 31;          // 0..31
        const int pos = posbase + pl;

        float A1 = s_b1[0][mm][pl]; int I1 = s_k1[0][mm][pl]; float A2 = s_b2[0][mm][pl];
        float B1 = s_b1[1][mm][pl]; int J1 = s_k1[1][mm][pl]; float B2 = s_b2[1][mm][pl];
        float b2m = fmaxf(fminf(A1, B1), fmaxf(A2, B2));
        bool awin = (A1 > B1) || (A1 == B1 && I1 < J1);
        float b1m = awin ? A1 : B1;
        int   K1  = awin ? I1 : J1;

        out[(size_t)pos * M_ + mm] = K1;  // fallback overwrites if unconfirmed

        bool conf = (b1m - b2m > GAPEPS); // pure-approx gap test (no fp32 pass)
        unsigned long long mask = __ballot(!conf);
        if (mask) {
            int leader = __ffsll(mask) - 1;
            int base = 0;
            if (L == leader) base = atomicAdd(cnt, (int)__popcll(mask));
            base = __shfl(base, leader);
            if (!conf) {
                unsigned long long below = mask & ((1ull << L) - 1ull);
                list[base + (int)__popcll(below)] = mm * NHW_ + pos;
            }
        }
    }
}

// ---- kernel 3: block-per-entry exact fp32 scan of all 2048 codes (rare) ----
// (R8-validated, unchanged)
__global__ __launch_bounds__(256) void fallback_kernel(
        const float* __restrict__ latent,
        const float* __restrict__ codebook,
        const int* __restrict__ cnt, const int* __restrict__ list,
        int* __restrict__ out) {
    __shared__ float s_bs[4];
    __shared__ int   s_bk[4];
    const int tid  = threadIdx.x;
    const int wave = tid >> 6;
    const int L    = tid & 63;
    const int ncnt = *cnt;

    for (int e = blockIdx.x; e < ncnt; e += gridDim.x) {
        int t   = list[e];
        int mm  = t >> 15;
        int pos = t & (NHW_ - 1);
        int n   = pos >> 12;
        int hw  = pos & (HW_ - 1);
        const float* lq = latent + ((size_t)n * (M_ * D_) + mm * D_) * HW_ + hw;
        float q[D_];
        #pragma unroll
        for (int d = 0; d < D_; ++d) q[d] = lq[(size_t)d * HW_];   // broadcast

        float bs = -3.402823466e+38f;
        int   bk = 0;
        #pragma unroll
        for (int i = 0; i < 8; ++i) {                  // k = tid + 256*i, ascending
            int k = tid + 256 * i;
            float s = score_fp32(q, (const float4*)(codebook + ((size_t)mm * K_ + k) * D_));
            if (s > bs || (s == bs && k < bk)) { bs = s; bk = k; }
        }
        #pragma unroll
        for (int off = 1; off <= 32; off <<= 1) {
            float os = __shfl_xor(bs, off);
            int   ok = __shfl_xor(bk, off);
            if (os > bs || (os == bs && ok < bk)) { bs = os; bk = ok; }
        }
        if (L == 0) { s_bs[wave] = bs; s_bk[wave] = bk; }
        __syncthreads();
        if (tid == 0) {
            float fs = s_bs[0]; int fk = s_bk[0];
            #pragma unroll
            for (int w = 1; w < 4; ++w) {
                float os = s_bs[w]; int ok = s_bk[w];
                if (os > fs || (os == fs && ok < fk)) { fs = os; fk = ok; }
            }
            out[(size_t)pos * M_ + mm] = fk;           // first-max over all k
        }
        __syncthreads();
    }
}

extern "C" void kernel_launch(void* const* d_in, const int* in_sizes, int n_in,
                              void* d_out, int out_size, void* d_ws, size_t ws_size,
                              hipStream_t stream) {
    const float* latent   = (const float*)d_in[0];
    const float* codebook = (const float*)d_in[1];
    unsigned char* ws = (unsigned char*)d_ws;
    int* out = (int*)d_out;
    prep_kernel<<<(M_ * K_) / 256, 256, 0, stream>>>(codebook, ws);
    score_kernel<<<NHW_ / 32, 512, 0, stream>>>(latent, ws,
                                                (int*)(ws + CNT_OFF),
                                                (int*)(ws + LIST_OFF),
                                                out);
    fallback_kernel<<<1024, 256, 0, stream>>>(latent, codebook,
                                              (const int*)(ws + CNT_OFF),
                                              (const int*)(ws + LIST_OFF),
                                              out);
}

// Round 11
// 119.240 us; speedup vs baseline: 1.1500x; 1.1500x over previous
//
#include <hip/hip_runtime.h>

#define M_ 4
#define K_ 2048
#define D_ 32
#define HW_ 4096
#define NHW_ 32768

// Gap-test margin (HW-validated R10, absmax=0): conf <=> b1m - b2m > GAPEPS.
// eps bound for 3-term bf16 split ~1.3e-3; GAPEPS = 0.01 ~ 4x margin.
// conf => K1 is the unique exact argmax; else exact fallback decides.
#define GAPEPS 0.01f

// workspace (bytes)
#define CH_OFF 0                        // bf16 hi codebook [4][2048][32] (512 KiB)
#define CL_OFF (M_*K_*D_*2)             // bf16 lo codebook              (512 KiB)
#define HN_OFF (CL_OFF*2)               // f32 -0.5*||c||^2 [4][2048]    (32 KiB)
#define CNT_OFF (HN_OFF + M_*K_*4)      // i32 unconfirmed count         (16 B)
#define LIST_OFF (CNT_OFF + 16)         // i32 unconfirmed ids [4*32768] (512 KiB)

typedef __attribute__((ext_vector_type(8))) short bf16x8;
typedef __attribute__((ext_vector_type(4))) float f32x4;

__device__ __forceinline__ short bf16_rte(float x, float* back) {
    unsigned u = __float_as_uint(x);
    unsigned r = (u + 0x7FFFu + ((u >> 16) & 1u)) >> 16;
    *back = __uint_as_float(r << 16);
    return (short)(r & 0xFFFFu);
}

// ---- kernel 1: codebook -> bf16 hi/lo + (-0.5*||c||^2); zero fallback cnt ----
__global__ __launch_bounds__(256) void prep_kernel(const float* __restrict__ cb,
                                                   unsigned char* __restrict__ ws) {
    if (blockIdx.x == 0 && threadIdx.x == 0) *(int*)(ws + CNT_OFF) = 0;
    int t = blockIdx.x * 256 + threadIdx.x;          // row id = m*K_ + k
    const float* src = cb + (size_t)t * D_;
    short* dh = (short*)(ws + CH_OFF) + (size_t)t * D_;
    short* dl = (short*)(ws + CL_OFF) + (size_t)t * D_;
    float* hn = (float*)(ws + HN_OFF);
    bf16x8 vh[4], vl[4];
    float c2 = 0.f;
    #pragma unroll
    for (int d = 0; d < D_; ++d) {
        float x = src[d];
        float hf, lf;
        short hb = bf16_rte(x, &hf);
        short lb = bf16_rte(x - hf, &lf);
        vh[d >> 3][d & 7] = hb;
        vl[d >> 3][d & 7] = lb;
        c2 = fmaf(x, x, c2);
    }
    #pragma unroll
    for (int i = 0; i < 4; ++i) {
        *(bf16x8*)(dh + i * 8) = vh[i];
        *(bf16x8*)(dl + i * 8) = vl[i];
    }
    hn[t] = -0.5f * c2;
}

__device__ __forceinline__ float score_fp32(const float* __restrict__ q,
                                            const float4* __restrict__ c) {
    float d0 = 0, d1 = 0, d2 = 0, d3 = 0, e0 = 0, e1 = 0, e2 = 0, e3 = 0;
    #pragma unroll
    for (int v = 0; v < 8; ++v) {
        float4 cv = c[v];
        d0 = fmaf(q[v * 4 + 0], cv.x, d0);
        d1 = fmaf(q[v * 4 + 1], cv.y, d1);
        d2 = fmaf(q[v * 4 + 2], cv.z, d2);
        d3 = fmaf(q[v * 4 + 3], cv.w, d3);
        e0 = fmaf(cv.x, cv.x, e0);
        e1 = fmaf(cv.y, cv.y, e1);
        e2 = fmaf(cv.z, cv.z, e2);
        e3 = fmaf(cv.w, cv.w, e3);
    }
    return ((d0 + d1) + (d2 + d3)) - 0.5f * ((e0 + e1) + (e2 + e3));
}

// ---- kernel 2: R8-validated score body (64-pos tiles, G=4) +
//      R10-validated fused gap-test epilogue ----
// 512 threads = 8 waves. wave w: m = w&3, kh = w>>2 (half of the codebook).
__global__ __launch_bounds__(512, 4) void score_kernel(
        const float* __restrict__ latent,
        const unsigned char* __restrict__ cws,
        int* __restrict__ cnt, int* __restrict__ list,
        int* __restrict__ out) {
    __shared__ float s_b1[2][M_][64];
    __shared__ int   s_k1[2][M_][64];
    __shared__ float s_b2[2][M_][64];

    const int tid  = threadIdx.x;
    const int wave = tid >> 6;
    const int L    = tid & 63;
    const int m    = wave & 3;
    const int kh   = wave >> 2;
    const int col  = L & 15;
    const int krow = L >> 4;
    const int posbase = blockIdx.x * 64;
    const int n   = posbase >> 12;
    const int hwb = posbase & (HW_ - 1);

    bf16x8 qh[4], ql[4];
    const float* lp = latent + ((size_t)n * (M_ * D_) + m * D_) * HW_ + hwb;
    #pragma unroll
    for (int g = 0; g < 4; ++g)
        #pragma unroll
        for (int j = 0; j < 8; ++j) {
            float x = lp[(size_t)(krow * 8 + j) * HW_ + g * 16 + col];
            float hf, lf;
            qh[g][j] = bf16_rte(x, &hf);
            ql[g][j] = bf16_rte(x - hf, &lf);
        }

    const short* ah = (const short*)(cws + CH_OFF)
                      + ((size_t)m * K_ + kh * 1024 + col) * D_ + krow * 8;
    const short* al = (const short*)(cws + CL_OFF)
                      + ((size_t)m * K_ + kh * 1024 + col) * D_ + krow * 8;
    const float* hn = (const float*)(cws + HN_OFF) + m * K_ + kh * 1024 + krow * 4;

    float b1[4], b2[4];
    int   k1[4];
    #pragma unroll
    for (int g = 0; g < 4; ++g) { b1[g] = b2[g] = -3.402823466e+38f; k1[g] = 0; }

    const int kbase = kh * 1024 + krow * 4;

    #pragma unroll 2
    for (int t = 0; t < 64; ++t) {
        bf16x8 ch = *(const bf16x8*)(ah + (size_t)t * (16 * D_));
        bf16x8 cl = *(const bf16x8*)(al + (size_t)t * (16 * D_));
        f32x4  c0 = *(const f32x4*)(hn + t * 16);
        const int kt = kbase + t * 16;
        #pragma unroll
        for (int g = 0; g < 4; ++g) {
            f32x4 a = __builtin_amdgcn_mfma_f32_16x16x32_bf16(cl, qh[g], c0, 0, 0, 0);
            a = __builtin_amdgcn_mfma_f32_16x16x32_bf16(ch, ql[g], a, 0, 0, 0);
            a = __builtin_amdgcn_mfma_f32_16x16x32_bf16(ch, qh[g], a, 0, 0, 0);
            #pragma unroll
            for (int r = 0; r < 4; ++r) {
                float s = a[r];
                b2[g] = __builtin_amdgcn_fmed3f(b1[g], b2[g], s);   // running 2nd-max
                bool gt = s > b1[g];                                // strict: first-max
                k1[g] = gt ? (kt + r) : k1[g];
                b1[g] = gt ? s : b1[g];
            }
        }
    }

    // in-wave butterfly merge over the 4 code-row lane-groups (R8-validated)
    #pragma unroll
    for (int g = 0; g < 4; ++g) {
        #pragma unroll
        for (int off = 16; off <= 32; off <<= 1) {
            float ob1 = __shfl_xor(b1[g], off);
            int   ok1 = __shfl_xor(k1[g], off);
            float ob2 = __shfl_xor(b2[g], off);
            float mn  = fminf(b1[g], ob1);
            b2[g] = fmaxf(mn, fmaxf(b2[g], ob2));
            bool awin = (b1[g] > ob1) || (b1[g] == ob1 && k1[g] < ok1);
            b1[g] = awin ? b1[g] : ob1;
            k1[g] = awin ? k1[g] : ok1;
        }
    }
    if (L < 16) {
        #pragma unroll
        for (int g = 0; g < 4; ++g) {
            s_b1[kh][m][g * 16 + L] = b1[g];
            s_k1[kh][m][g * 16 + L] = k1[g];
            s_b2[kh][m][g * 16 + L] = b2[g];
        }
    }
    __syncthreads();

    // fused epilogue (R10-validated): merge halves, gap test, write, append
    if (tid < 256) {
        const int mm = tid >> 6;          // wave id 0..3 == m
        const int pl = tid & 63;
        const int pos = posbase + pl;

        float A1 = s_b1[0][mm][pl]; int I1 = s_k1[0][mm][pl]; float A2 = s_b2[0][mm][pl];
        float B1 = s_b1[1][mm][pl]; int J1 = s_k1[1][mm][pl]; float B2 = s_b2[1][mm][pl];
        float b2m = fmaxf(fminf(A1, B1), fmaxf(A2, B2));
        bool awin = (A1 > B1) || (A1 == B1 && I1 < J1);
        float b1m = awin ? A1 : B1;
        int   K1  = awin ? I1 : J1;

        out[(size_t)pos * M_ + mm] = K1;  // fallback overwrites if unconfirmed

        bool conf = (b1m - b2m > GAPEPS); // pure-approx gap test
        unsigned long long mask = __ballot(!conf);
        if (mask) {
            int leader = __ffsll(mask) - 1;
            int base = 0;
            if (L == leader) base = atomicAdd(cnt, (int)__popcll(mask));
            base = __shfl(base, leader);
            if (!conf) {
                unsigned long long below = mask & ((1ull << L) - 1ull);
                list[base + (int)__popcll(below)] = mm * NHW_ + pos;
            }
        }
    }
}

// ---- kernel 3: block-per-entry exact fp32 scan of all 2048 codes (rare) ----
// (R8-validated, unchanged)
__global__ __launch_bounds__(256) void fallback_kernel(
        const float* __restrict__ latent,
        const float* __restrict__ codebook,
        const int* __restrict__ cnt, const int* __restrict__ list,
        int* __restrict__ out) {
    __shared__ float s_bs[4];
    __shared__ int   s_bk[4];
    const int tid  = threadIdx.x;
    const int wave = tid >> 6;
    const int L    = tid & 63;
    const int ncnt = *cnt;

    for (int e = blockIdx.x; e < ncnt; e += gridDim.x) {
        int t   = list[e];
        int mm  = t >> 15;
        int pos = t & (NHW_ - 1);
        int n   = pos >> 12;
        int hw  = pos & (HW_ - 1);
        const float* lq = latent + ((size_t)n * (M_ * D_) + mm * D_) * HW_ + hw;
        float q[D_];
        #pragma unroll
        for (int d = 0; d < D_; ++d) q[d] = lq[(size_t)d * HW_];   // broadcast

        float bs = -3.402823466e+38f;
        int   bk = 0;
        #pragma unroll
        for (int i = 0; i < 8; ++i) {                  // k = tid + 256*i, ascending
            int k = tid + 256 * i;
            float s = score_fp32(q, (const float4*)(codebook + ((size_t)mm * K_ + k) * D_));
            if (s > bs || (s == bs && k < bk)) { bs = s; bk = k; }
        }
        #pragma unroll
        for (int off = 1; off <= 32; off <<= 1) {
            float os = __shfl_xor(bs, off);
            int   ok = __shfl_xor(bk, off);
            if (os > bs || (os == bs && ok < bk)) { bs = os; bk = ok; }
        }
        if (L == 0) { s_bs[wave] = bs; s_bk[wave] = bk; }
        __syncthreads();
        if (tid == 0) {
            float fs = s_bs[0]; int fk = s_bk[0];
            #pragma unroll
            for (int w = 1; w < 4; ++w) {
                float os = s_bs[w]; int ok = s_bk[w];
                if (os > fs || (os == fs && ok < fk)) { fs = os; fk = ok; }
            }
            out[(size_t)pos * M_ + mm] = fk;           // first-max over all k
        }
        __syncthreads();
    }
}

extern "C" void kernel_launch(void* const* d_in, const int* in_sizes, int n_in,
                              void* d_out, int out_size, void* d_ws, size_t ws_size,
                              hipStream_t stream) {
    const float* latent   = (const float*)d_in[0];
    const float* codebook = (const float*)d_in[1];
    unsigned char* ws = (unsigned char*)d_ws;
    int* out = (int*)d_out;
    prep_kernel<<<(M_ * K_) / 256, 256, 0, stream>>>(codebook, ws);
    score_kernel<<<NHW_ / 64, 512, 0, stream>>>(latent, ws,
                                                (int*)(ws + CNT_OFF),
                                                (int*)(ws + LIST_OFF),
                                                out);
    fallback_kernel<<<1024, 256, 0, stream>>>(latent, codebook,
                                              (const int*)(ws + CNT_OFF),
                                              (const int*)(ws + LIST_OFF),
                                              out);
}